// Round 4
// baseline (108.660 us; speedup 1.0000x reference)
//
#include <hip/hip_runtime.h>
#include <hip/hip_bf16.h>

#define DIM 128
// G=4 fan groups (proven round-3 split): [0,17) [17,38) [38,64) [64,127)
// ws floats: A0@0 (128^2) A1@16384 (111^2) A2@28705 (90^2) A3@36805 (64^2) end 40901
// Mb (bf16 M, row-major [128][128]) at byte 163616; total ws 196384 B (proven budget).

typedef __attribute__((ext_vector_type(4))) float f32x4;
typedef __attribute__((ext_vector_type(8))) short bf16x8;

__device__ __forceinline__ unsigned short f2bf(float f) {
  union { float f; unsigned int u; } v; v.f = f;
  unsigned int u = v.u;
  return (unsigned short)((u + 0x7FFFu + ((u >> 16) & 1u)) >> 16);
}

__device__ __forceinline__ void load_lds16(const float* src, float* dst) {
  __builtin_amdgcn_global_load_lds((const __attribute__((address_space(1))) void*)src,
                                   (__attribute__((address_space(3))) void*)dst, 16, 0, 0);
}

// pair-p geometry for a group of width N: f1=2p; window start (16B-aligned in col)
__device__ __forceinline__ int pair_start(int p) { return 2 * p + ((p & 1) << 1); }
__device__ __forceinline__ int pair_Lp(int N, int p) {
  const int fp = (p & 1) ? 0 : 2;            // front pad so window start%4==0
  const int len = N - 2 * p - 2;             // real inner length (>=0)
  return (fp + len + 15) & ~15;
}

// ---- K1: 4 concurrent group products; col in LDS (stride 148), batched epochs ----
template<int LO, int N, int P, int RB, int RE>
__device__ void build_group(const float* __restrict__ angles, float* __restrict__ A,
                            float* __restrict__ col, float4* __restrict__ cs) {
  const int t = threadIdx.x;
  // init cs to identity quads (c1,s1,c2,s2)=(1,0,1,0)
  for (int k = t; k < 1248; k += 256) { float4 v; v.x = 1.f; v.y = 0.f; v.z = 1.f; v.w = 0.f; cs[k] = v; }
  __syncthreads();
  // prologue: sincos -> padded pair-stream slots
  for (int r0 = RB + t; r0 < RE; r0 += 256) {
    int i = (int)floorf((255.0f - sqrtf(65025.0f - 8.0f * (float)r0)) * 0.5f);
    if (i < 0) i = 0; if (i > 126) i = 126;
    while (127 * (i + 1) - ((i + 1) * i) / 2 <= r0) ++i;
    while (127 * i - (i * (i - 1)) / 2 > r0) --i;
    const int Ti = 127 * i - (i * (i - 1)) / 2;
    const int j  = i + 1 + (r0 - Ti);
    const int fl = i - LO, p = fl >> 1, sec = fl & 1;
    int bp = 0;
    for (int q = 0; q < p; ++q) bp += 1 + pair_Lp(N, q);
    float s, c; __sincosf(angles[r0], &s, &c);
    const int jloc = j - LO;
    if (sec == 0 && jloc == 2 * p + 1) {
      *(float2*)&cs[bp] = (float2){c, s};                       // peel slot (x,y)
    } else {
      const int slot = bp + 1 + (jloc - pair_start(p));
      *((float2*)&cs[slot] + sec) = (float2){c, s};             // (x,y) rot1 / (z,w) rot2
    }
  }
  __syncthreads();
  if (t >= N) return;

  float* myc = col + t * 148;
  for (int r = 0; r < 148; ++r) myc[r] = (r == t) ? 1.0f : 0.0f;

  int base = 0;
  #pragma unroll 1
  for (int p = 0; p < P; ++p) {
    const int f1 = 2 * p;
    const int st = pair_start(p);
    const int Lp = pair_Lp(N, p);
    // peel: rotation (f1, f1+1)
    const float4 e0 = cs[base];
    float r1 = myc[f1];
    const float rj = myc[f1 + 1];
    float r2 = fmaf(e0.y, r1, e0.x * rj);
    r1 = fmaf(e0.x, r1, -(e0.y * rj));
    #pragma unroll 1
    for (int jb = 0; jb < Lp; jb += 16) {
      f32x4 v[4]; float4 e[16];
      #pragma unroll
      for (int q = 0; q < 4; ++q) v[q] = *(f32x4*)&myc[st + jb + 4 * q];
      #pragma unroll
      for (int q = 0; q < 16; ++q) e[q] = cs[base + 1 + jb + q];
      #pragma unroll
      for (int q = 0; q < 16; ++q) {
        const float rv = v[q >> 2][q & 3];
        const float wv = fmaf(e[q].y, r1, e[q].x * rv);   // rot1 new row j
        r1 = fmaf(e[q].x, r1, -(e[q].y * rv));            // rot1 new row f1 (chain)
        v[q >> 2][q & 3] = fmaf(e[q].w, r2, e[q].z * wv); // rot2 new row j
        r2 = fmaf(e[q].z, r2, -(e[q].w * wv));            // rot2 new row f1+1
      }
      #pragma unroll
      for (int q = 0; q < 4; ++q) *(f32x4*)&myc[st + jb + 4 * q] = v[q];
    }
    myc[f1] = r1;
    myc[f1 + 1] = r2;
    base += 1 + Lp;
  }
  for (int r = 0; r < N; ++r) A[r * N + t] = myc[r];   // coalesced across lanes
}

__global__ __launch_bounds__(256, 1) void k_build(const float* __restrict__ angles,
                                                  float* __restrict__ ws) {
  __shared__ float  col[128 * 148];   // 75.8 KB; stride 148 dw -> 2-way banks max
  __shared__ float4 cs[1248];         // 20 KB padded pair-stream
  switch (blockIdx.x) {
    case 0: build_group< 0, 128,  9,    0, 2023>(angles, ws,         col, cs); break;
    case 1: build_group<17, 111, 11, 2023, 4123>(angles, ws + 16384, col, cs); break;
    case 2: build_group<38,  90, 13, 4123, 6112>(angles, ws + 28705, col, cs); break;
    default: build_group<64, 64, 32, 6112, 8128>(angles, ws + 36805, col, cs); break;
  }
}

// ---- K2: column c of M = A3*A2*A1*A0*e_c via 4 chained matvecs ----
__global__ __launch_bounds__(128) void k_combine(const float* __restrict__ ws,
                                                 unsigned short* __restrict__ Mb) {
  __shared__ float x[DIM];
  const int c = blockIdx.x, r = threadIdx.x;
  x[r] = (r == c) ? 1.0f : 0.0f;
  __syncthreads();
  const int LOs[4]  = {0, 17, 38, 64};
  const int Ns[4]   = {128, 111, 90, 64};
  const int offs[4] = {0, 16384, 28705, 36805};
  #pragma unroll
  for (int g = 0; g < 4; ++g) {
    const int lo = LOs[g], n = Ns[g];
    float y;
    if (r >= lo) {
      const float* Ar = ws + offs[g] + (r - lo) * n;
      float acc = 0.0f;
      #pragma unroll 8
      for (int k = 0; k < n; ++k) acc = fmaf(Ar[k], x[lo + k], acc);
      y = acc;
    } else {
      y = x[r];
    }
    __syncthreads();
    x[r] = y;
    __syncthreads();
  }
  Mb[r * DIM + c] = f2bf(x[r]);
}

// ---- K3: out = X @ M^T + bias; X staged via global_load_lds w/ source-side swizzle ----
__global__ __launch_bounds__(256) void k_gemm(const float* __restrict__ X,
                                              const float* __restrict__ bias,
                                              const unsigned short* __restrict__ Mb,
                                              float* __restrict__ out) {
  __shared__ float Xs[128 * 128];              // 64 KB fp32 tile, swizzled by 32B units
  const int t = threadIdx.x;
  const int lane = t & 63, wid = t >> 6;
  const int l15 = lane & 15, lhi = lane >> 4;
  const float* Xblk = X + (size_t)blockIdx.x * 16384;

  // stage 64 KB: LDS linear dest, global source pre-swizzled (unit u -> u^(r&15))
  #pragma unroll
  for (int it = 0; it < 16; ++it) {
    const int g = (it * 4 + wid) * 64 + lane;  // 16B-chunk dest index
    const int r = g >> 5, kc = g & 31;
    const int pu = (kc >> 1) ^ (r & 15), h = kc & 1;
    load_lds16(Xblk + r * 128 + pu * 8 + h * 4, &Xs[(it * 4 + wid) * 256]);
  }
  __syncthreads();

  f32x4 acc[2][8];
  #pragma unroll
  for (int m = 0; m < 2; ++m)
    #pragma unroll
    for (int n = 0; n < 8; ++n) acc[m][n] = (f32x4){0.f, 0.f, 0.f, 0.f};

  // A fragments from swizzled LDS: row r, unit u=kt*4+lhi at physical u^(r&15)
  bf16x8 a[2][4];
  #pragma unroll
  for (int mt = 0; mt < 2; ++mt) {
    const int r = wid * 32 + mt * 16 + l15;
    #pragma unroll
    for (int kt = 0; kt < 4; ++kt) {
      const int pu = (kt * 4 + lhi) ^ (r & 15);
      const float* p = &Xs[r * 128 + pu * 8];
      const f32x4 x0 = *(const f32x4*)p;
      const f32x4 x1 = *(const f32x4*)(p + 4);
      bf16x8 av;
      av[0] = (short)f2bf(x0[0]); av[1] = (short)f2bf(x0[1]);
      av[2] = (short)f2bf(x0[2]); av[3] = (short)f2bf(x0[3]);
      av[4] = (short)f2bf(x1[0]); av[5] = (short)f2bf(x1[1]);
      av[6] = (short)f2bf(x1[2]); av[7] = (short)f2bf(x1[3]);
      a[mt][kt] = av;
    }
  }

  #pragma unroll
  for (int kt = 0; kt < 4; ++kt) {
    #pragma unroll
    for (int n = 0; n < 8; ++n) {
      const bf16x8 b = *(const bf16x8*)(Mb + ((l15 + 16 * n) * DIM + kt * 32 + lhi * 8));
      acc[0][n] = __builtin_amdgcn_mfma_f32_16x16x32_bf16(a[0][kt], b, acc[0][n], 0, 0, 0);
      acc[1][n] = __builtin_amdgcn_mfma_f32_16x16x32_bf16(a[1][kt], b, acc[1][n], 0, 0, 0);
    }
  }

  const int rowbase = blockIdx.x * 128 + wid * 32;
  #pragma unroll
  for (int n = 0; n < 8; ++n) {
    const float bs = bias[16 * n + l15];
    #pragma unroll
    for (int mt = 0; mt < 2; ++mt) {
      const int rb = rowbase + mt * 16 + lhi * 4;
      #pragma unroll
      for (int j = 0; j < 4; ++j)
        out[(rb + j) * DIM + 16 * n + l15] = acc[mt][n][j] + bs;
    }
  }
}

extern "C" void kernel_launch(void* const* d_in, const int* in_sizes, int n_in,
                              void* d_out, int out_size, void* d_ws, size_t ws_size,
                              hipStream_t stream) {
  const float* x      = (const float*)d_in[0];
  const float* angles = (const float*)d_in[1];
  const float* bias   = (const float*)d_in[2];
  float* out = (float*)d_out;
  float* ws  = (float*)d_ws;
  unsigned short* Mb = (unsigned short*)((char*)d_ws + 163616);

  k_build<<<4, 256, 0, stream>>>(angles, ws);
  k_combine<<<128, 128, 0, stream>>>(ws, Mb);
  k_gemm<<<1024, 256, 0, stream>>>(x, bias, Mb, out);
}